// Round 1
// baseline (332.015 us; speedup 1.0000x reference)
//
#include <hip/hip_runtime.h>

#define EPSF 1e-8f
#define PROB_PENALTYF 1e-4f
#define REV_SCALEF 0.1f

#define BLK 256

// ---------------- kernel 0: init workspace ----------------
__global__ void init_ws_kernel(float* acc, unsigned int* fwd_min,
                               unsigned int* rev_min, int fs, int npts) {
    int i = blockIdx.x * blockDim.x + threadIdx.x;
    if (i == 0) {
        acc[0] = 0.0f;                       // forward weighted sum (+ penalty)
        acc[1] = 0.0f;                       // reverse weighted sum (unscaled)
        ((unsigned int*)acc)[2] = 0u;        // reverse max (float bits)
    }
    if (i < fs)   fwd_min[i] = 0x7F800000u;  // +inf
    if (i < npts) rev_min[i] = 0x7F800000u;  // +inf
}

// ---------------- kernel 1: original barycenters ----------------
__global__ void bary_kernel(const float* __restrict__ verts,
                            const int* __restrict__ faces,
                            float* __restrict__ bc, int nfaces) {
    int i = blockIdx.x * blockDim.x + threadIdx.x;
    if (i >= nfaces) return;
    int a = faces[i * 3 + 0], b = faces[i * 3 + 1], c = faces[i * 3 + 2];
    const float k = 1.0f / 3.0f;
    bc[i * 3 + 0] = (verts[a * 3 + 0] + verts[b * 3 + 0] + verts[c * 3 + 0]) * k;
    bc[i * 3 + 1] = (verts[a * 3 + 1] + verts[b * 3 + 1] + verts[c * 3 + 1]) * k;
    bc[i * 3 + 2] = (verts[a * 3 + 2] + verts[b * 3 + 2] + verts[c * 3 + 2]) * k;
}

// ---------------- kernel 2: forward min d2 (simp bc -> orig bc) ----------------
// grid.x over simplified faces (1 per thread), grid.y over column chunks
__global__ void fwd_min_kernel(const float* __restrict__ sverts,
                               const int* __restrict__ sfaces,
                               const float* __restrict__ obc,
                               unsigned int* __restrict__ fwd_min,
                               int fs, int fo, int chunk) {
    __shared__ float tile[BLK * 3];
    int f = blockIdx.x * blockDim.x + threadIdx.x;
    bool valid = (f < fs);
    float px = 0.f, py = 0.f, pz = 0.f;
    if (valid) {
        int a = sfaces[f * 3 + 0], b = sfaces[f * 3 + 1], c = sfaces[f * 3 + 2];
        const float k = 1.0f / 3.0f;
        px = (sverts[a * 3 + 0] + sverts[b * 3 + 0] + sverts[c * 3 + 0]) * k;
        py = (sverts[a * 3 + 1] + sverts[b * 3 + 1] + sverts[c * 3 + 1]) * k;
        pz = (sverts[a * 3 + 2] + sverts[b * 3 + 2] + sverts[c * 3 + 2]) * k;
    }
    int start = blockIdx.y * chunk;
    int end = min(start + chunk, fo);
    float m = __uint_as_float(0x7F800000u);
    for (int base = start; base < end; base += BLK) {
        int n = min(BLK, end - base);
        __syncthreads();
        if ((int)threadIdx.x < n) {
            int g = base + (int)threadIdx.x;
            tile[threadIdx.x * 3 + 0] = obc[g * 3 + 0];
            tile[threadIdx.x * 3 + 1] = obc[g * 3 + 1];
            tile[threadIdx.x * 3 + 2] = obc[g * 3 + 2];
        }
        __syncthreads();
        #pragma unroll 4
        for (int j = 0; j < n; ++j) {
            float dx = px - tile[j * 3 + 0];
            float dy = py - tile[j * 3 + 1];
            float dz = pz - tile[j * 3 + 2];
            float d2 = dx * dx + dy * dy + dz * dz;
            m = fminf(m, d2);
        }
    }
    if (valid) atomicMin(&fwd_min[f], __float_as_uint(m));
}

// ---------------- kernel 3: reverse min d2 (sample pts -> orig verts) ----------------
// grid.x over sample points (1 per thread), grid.y over vertex chunks
__global__ void rev_min_kernel(const float* __restrict__ sverts,
                               const int* __restrict__ sfaces,
                               const float* __restrict__ u1,
                               const float* __restrict__ u2,
                               const float* __restrict__ overts,
                               unsigned int* __restrict__ rev_min,
                               int fs, int S, int no, int chunk) {
    __shared__ float tile[BLK * 3];
    int k = blockIdx.x * blockDim.x + threadIdx.x;
    int npts = fs * S;
    bool valid = (k < npts);
    float px = 0.f, py = 0.f, pz = 0.f;
    if (valid) {
        int f = k / S;
        float r1 = sqrtf(u1[k]);
        float uu2 = u2[k];
        float wa = 1.0f - r1;
        float wb = r1 * (1.0f - uu2);
        float wc = r1 * uu2;
        int a = sfaces[f * 3 + 0], b = sfaces[f * 3 + 1], c = sfaces[f * 3 + 2];
        px = wa * sverts[a * 3 + 0] + wb * sverts[b * 3 + 0] + wc * sverts[c * 3 + 0];
        py = wa * sverts[a * 3 + 1] + wb * sverts[b * 3 + 1] + wc * sverts[c * 3 + 1];
        pz = wa * sverts[a * 3 + 2] + wb * sverts[b * 3 + 2] + wc * sverts[c * 3 + 2];
    }
    int start = blockIdx.y * chunk;
    int end = min(start + chunk, no);
    float m = __uint_as_float(0x7F800000u);
    for (int base = start; base < end; base += BLK) {
        int n = min(BLK, end - base);
        __syncthreads();
        if ((int)threadIdx.x < n) {
            int g = base + (int)threadIdx.x;
            tile[threadIdx.x * 3 + 0] = overts[g * 3 + 0];
            tile[threadIdx.x * 3 + 1] = overts[g * 3 + 1];
            tile[threadIdx.x * 3 + 2] = overts[g * 3 + 2];
        }
        __syncthreads();
        #pragma unroll 4
        for (int j = 0; j < n; ++j) {
            float dx = px - tile[j * 3 + 0];
            float dy = py - tile[j * 3 + 1];
            float dz = pz - tile[j * 3 + 2];
            float d2 = dx * dx + dy * dy + dz * dz;
            m = fminf(m, d2);
        }
    }
    if (valid) atomicMin(&rev_min[k], __float_as_uint(m));
}

// ---------------- kernel 4: reductions ----------------
__global__ void finalize_partial_kernel(const unsigned int* __restrict__ fwd_min,
                                        const unsigned int* __restrict__ rev_min,
                                        const float* __restrict__ fp,
                                        float* acc, int fs, int npts, int S) {
    __shared__ float s1[BLK], s2[BLK], s3[BLK];
    int k = blockIdx.x * blockDim.x + threadIdx.x;
    float fsum = 0.f, rsum = 0.f, rmax = 0.f;
    if (k < npts) {
        float md = __uint_as_float(rev_min[k]);
        float p = fp[k / S];
        rsum = p * md;
        rmax = md;
    }
    if (k < fs) {
        float p = fp[k];
        fsum = p * __uint_as_float(fwd_min[k]) + PROB_PENALTYF * (1.0f - p);
    }
    s1[threadIdx.x] = fsum;
    s2[threadIdx.x] = rsum;
    s3[threadIdx.x] = rmax;
    __syncthreads();
    for (int off = BLK / 2; off > 0; off >>= 1) {
        if ((int)threadIdx.x < off) {
            s1[threadIdx.x] += s1[threadIdx.x + off];
            s2[threadIdx.x] += s2[threadIdx.x + off];
            s3[threadIdx.x] = fmaxf(s3[threadIdx.x], s3[threadIdx.x + off]);
        }
        __syncthreads();
    }
    if (threadIdx.x == 0) {
        atomicAdd(&acc[0], s1[0]);
        atomicAdd(&acc[1], s2[0]);
        atomicMax((unsigned int*)&acc[2], __float_as_uint(s3[0]));
    }
}

// ---------------- kernel 5: final scalar ----------------
__global__ void write_out_kernel(const float* acc, float* out) {
    float mx = __uint_as_float(((const unsigned int*)acc)[2]);
    out[0] = acc[0] + acc[1] * (REV_SCALEF / (mx + EPSF));
}

extern "C" void kernel_launch(void* const* d_in, const int* in_sizes, int n_in,
                              void* d_out, int out_size, void* d_ws, size_t ws_size,
                              hipStream_t stream) {
    const float* overts = (const float*)d_in[0];
    const int*   ofaces = (const int*)d_in[1];
    const float* sverts = (const float*)d_in[2];
    const int*   sfaces = (const int*)d_in[3];
    const float* fp     = (const float*)d_in[4];
    const float* u1     = (const float*)d_in[5];
    const float* u2     = (const float*)d_in[6];
    float* out = (float*)d_out;

    const int N_ORIG = in_sizes[0] / 3;
    const int F_ORIG = in_sizes[1] / 3;
    const int F_SIMP = in_sizes[3] / 3;
    const int S      = in_sizes[5] / F_SIMP;
    const int NPTS   = F_SIMP * S;

    // workspace layout (floats)
    float* ws = (float*)d_ws;
    float* acc = ws;                                   // 16 floats reserved
    float* obc = ws + 16;                              // F_ORIG*3
    unsigned int* fwd_min = (unsigned int*)(obc + F_ORIG * 3);  // F_SIMP
    unsigned int* rev_min = fwd_min + F_SIMP;                    // NPTS

    int initN = max(NPTS, F_SIMP);
    hipLaunchKernelGGL(init_ws_kernel, dim3((initN + BLK - 1) / BLK), dim3(BLK), 0, stream,
                       acc, fwd_min, rev_min, F_SIMP, NPTS);

    hipLaunchKernelGGL(bary_kernel, dim3((F_ORIG + BLK - 1) / BLK), dim3(BLK), 0, stream,
                       overts, ofaces, obc, F_ORIG);

    const int FWD_CHUNKS = 8;
    int fwd_chunk = (F_ORIG + FWD_CHUNKS - 1) / FWD_CHUNKS;
    hipLaunchKernelGGL(fwd_min_kernel,
                       dim3((F_SIMP + BLK - 1) / BLK, FWD_CHUNKS), dim3(BLK), 0, stream,
                       sverts, sfaces, obc, fwd_min, F_SIMP, F_ORIG, fwd_chunk);

    const int REV_CHUNKS = 4;
    int rev_chunk = (N_ORIG + REV_CHUNKS - 1) / REV_CHUNKS;
    hipLaunchKernelGGL(rev_min_kernel,
                       dim3((NPTS + BLK - 1) / BLK, REV_CHUNKS), dim3(BLK), 0, stream,
                       sverts, sfaces, u1, u2, overts, rev_min, F_SIMP, S, N_ORIG, rev_chunk);

    hipLaunchKernelGGL(finalize_partial_kernel, dim3((NPTS + BLK - 1) / BLK), dim3(BLK), 0, stream,
                       fwd_min, rev_min, fp, acc, F_SIMP, NPTS, S);

    hipLaunchKernelGGL(write_out_kernel, dim3(1), dim3(1), 0, stream, acc, out);
}

// Round 2
// 51.672 us; speedup vs baseline: 6.4254x; 6.4254x over previous
//
#include <hip/hip_runtime.h>

#define EPSF 1e-8f
#define PROB_PENALTYF 1e-4f
#define REV_SCALEF 0.1f

#define BLK 256
#define P 8
#define INFBITS 0x7F800000u

// ---------------- kernel 0: prep (barycenters+|.|^2, verts+|.|^2, init) ----------------
__global__ void prep_kernel(const float* __restrict__ overts,
                            const int* __restrict__ ofaces,
                            float4* __restrict__ obc4,
                            float4* __restrict__ overts4,
                            unsigned int* __restrict__ fwd_min,
                            unsigned int* __restrict__ rev_min,
                            float* acc,
                            int n_orig, int f_orig, int fs, int npts) {
    int i = blockIdx.x * blockDim.x + threadIdx.x;
    if (i == 0) {
        acc[0] = 0.0f;
        acc[1] = 0.0f;
        ((unsigned int*)acc)[2] = 0u;
    }
    if (i < f_orig) {
        int a = ofaces[3 * i], b = ofaces[3 * i + 1], c = ofaces[3 * i + 2];
        const float k = 1.0f / 3.0f;
        float x = (overts[3 * a] + overts[3 * b] + overts[3 * c]) * k;
        float y = (overts[3 * a + 1] + overts[3 * b + 1] + overts[3 * c + 1]) * k;
        float z = (overts[3 * a + 2] + overts[3 * b + 2] + overts[3 * c + 2]) * k;
        obc4[i] = make_float4(x, y, z, x * x + y * y + z * z);
    }
    if (i < n_orig) {
        float x = overts[3 * i], y = overts[3 * i + 1], z = overts[3 * i + 2];
        overts4[i] = make_float4(x, y, z, x * x + y * y + z * z);
    }
    if (i < fs)   fwd_min[i] = INFBITS;
    if (i < npts) rev_min[i] = INFBITS;
}

// ---------------- kernel 1: fused fwd+rev min-distance ----------------
// blocks [0, fwdBlocks): forward term (simp barycenters vs orig barycenters)
// blocks [fwdBlocks, ..): reverse term (sampled points vs orig vertices)
// Each thread owns P points; each block covers one vertex-chunk; per-point
// result merged across chunks via atomicMin on float bits (values clamped >= 0).
__global__ void min_kernel(const float* __restrict__ sverts,
                           const int* __restrict__ sfaces,
                           const float* __restrict__ u1,
                           const float* __restrict__ u2,
                           const float4* __restrict__ obc4,
                           const float4* __restrict__ overts4,
                           unsigned int* __restrict__ fwd_min,
                           unsigned int* __restrict__ rev_min,
                           int fs, int S,
                           int fwdBlocks, int fwdPtBlocks, int fwdChunk, int f_orig,
                           int revPtBlocks, int revChunk, int n_orig) {
    __shared__ float4 tile[BLK];
    int bid = blockIdx.x;
    int t = threadIdx.x;

    bool isFwd = (bid < fwdBlocks);
    const float4* src;
    unsigned int* outmin;
    int nsrc, npts, pb, cb, chunk;
    if (isFwd) {
        src = obc4; outmin = fwd_min; nsrc = f_orig; npts = fs;
        pb = bid % fwdPtBlocks; cb = bid / fwdPtBlocks; chunk = fwdChunk;
    } else {
        int b = bid - fwdBlocks;
        src = overts4; outmin = rev_min; nsrc = n_orig; npts = fs * S;
        pb = b % revPtBlocks; cb = b / revPtBlocks; chunk = revChunk;
    }

    int pbase = pb * BLK * P;
    float px[P], py[P], pz[P], p2[P], m[P];
    bool val[P];
    const float third = 1.0f / 3.0f;

    #pragma unroll
    for (int i = 0; i < P; ++i) {
        int k = pbase + i * BLK + t;
        val[i] = (k < npts);
        float x = 0.f, y = 0.f, z = 0.f;
        if (val[i]) {
            if (isFwd) {
                int a = sfaces[3 * k], b = sfaces[3 * k + 1], c = sfaces[3 * k + 2];
                x = (sverts[3 * a] + sverts[3 * b] + sverts[3 * c]) * third;
                y = (sverts[3 * a + 1] + sverts[3 * b + 1] + sverts[3 * c + 1]) * third;
                z = (sverts[3 * a + 2] + sverts[3 * b + 2] + sverts[3 * c + 2]) * third;
            } else {
                int f = k / S;
                float r1 = sqrtf(u1[k]);
                float uu2 = u2[k];
                float wa = 1.0f - r1;
                float wb = r1 * (1.0f - uu2);
                float wc = r1 * uu2;
                int a = sfaces[3 * f], b = sfaces[3 * f + 1], c = sfaces[3 * f + 2];
                x = wa * sverts[3 * a] + wb * sverts[3 * b] + wc * sverts[3 * c];
                y = wa * sverts[3 * a + 1] + wb * sverts[3 * b + 1] + wc * sverts[3 * c + 1];
                z = wa * sverts[3 * a + 2] + wb * sverts[3 * b + 2] + wc * sverts[3 * c + 2];
            }
        }
        p2[i] = x * x + y * y + z * z;
        px[i] = -2.0f * x;   // pre-scaled for fma chain
        py[i] = -2.0f * y;
        pz[i] = -2.0f * z;
        m[i] = __uint_as_float(INFBITS);
    }

    int start = cb * chunk;
    int end = min(start + chunk, nsrc);
    for (int base = start; base < end; base += BLK) {
        int n = min(BLK, end - base);
        __syncthreads();
        if (t < n) tile[t] = src[base + t];
        __syncthreads();
        for (int j = 0; j < n; ++j) {
            float4 v = tile[j];
            #pragma unroll
            for (int i = 0; i < P; ++i) {
                float s = fmaf(px[i], v.x, v.w);   // |v|^2 - 2 p.v (3 fma)
                s = fmaf(py[i], v.y, s);
                s = fmaf(pz[i], v.z, s);
                m[i] = fminf(m[i], s);
            }
        }
    }

    #pragma unroll
    for (int i = 0; i < P; ++i) {
        if (val[i]) {
            float d2 = fmaxf(p2[i] + m[i], 0.0f);  // clamp tiny fp negatives
            atomicMin(&outmin[pbase + i * BLK + t], __float_as_uint(d2));
        }
    }
}

// ---------------- kernel 2: reductions ----------------
__global__ void finalize_partial_kernel(const unsigned int* __restrict__ fwd_min,
                                        const unsigned int* __restrict__ rev_min,
                                        const float* __restrict__ fp,
                                        float* acc, int fs, int npts, int S) {
    __shared__ float s1[BLK], s2[BLK], s3[BLK];
    int k = blockIdx.x * blockDim.x + threadIdx.x;
    float fsum = 0.f, rsum = 0.f, rmax = 0.f;
    if (k < npts) {
        float md = __uint_as_float(rev_min[k]);
        float p = fp[k / S];
        rsum = p * md;
        rmax = md;
    }
    if (k < fs) {
        float p = fp[k];
        fsum = p * __uint_as_float(fwd_min[k]) + PROB_PENALTYF * (1.0f - p);
    }
    s1[threadIdx.x] = fsum;
    s2[threadIdx.x] = rsum;
    s3[threadIdx.x] = rmax;
    __syncthreads();
    for (int off = BLK / 2; off > 0; off >>= 1) {
        if ((int)threadIdx.x < off) {
            s1[threadIdx.x] += s1[threadIdx.x + off];
            s2[threadIdx.x] += s2[threadIdx.x + off];
            s3[threadIdx.x] = fmaxf(s3[threadIdx.x], s3[threadIdx.x + off]);
        }
        __syncthreads();
    }
    if (threadIdx.x == 0) {
        atomicAdd(&acc[0], s1[0]);
        atomicAdd(&acc[1], s2[0]);
        atomicMax((unsigned int*)&acc[2], __float_as_uint(s3[0]));
    }
}

// ---------------- kernel 3: final scalar ----------------
__global__ void write_out_kernel(const float* acc, float* out) {
    float mx = __uint_as_float(((const unsigned int*)acc)[2]);
    out[0] = acc[0] + acc[1] * (REV_SCALEF / (mx + EPSF));
}

extern "C" void kernel_launch(void* const* d_in, const int* in_sizes, int n_in,
                              void* d_out, int out_size, void* d_ws, size_t ws_size,
                              hipStream_t stream) {
    const float* overts = (const float*)d_in[0];
    const int*   ofaces = (const int*)d_in[1];
    const float* sverts = (const float*)d_in[2];
    const int*   sfaces = (const int*)d_in[3];
    const float* fp     = (const float*)d_in[4];
    const float* u1     = (const float*)d_in[5];
    const float* u2     = (const float*)d_in[6];
    float* out = (float*)d_out;

    const int N_ORIG = in_sizes[0] / 3;
    const int F_ORIG = in_sizes[1] / 3;
    const int F_SIMP = in_sizes[3] / 3;
    const int S      = in_sizes[5] / F_SIMP;
    const int NPTS   = F_SIMP * S;

    // workspace layout (16B-aligned float4 arrays first)
    float4* obc4    = (float4*)d_ws;                 // F_ORIG
    float4* overts4 = obc4 + F_ORIG;                 // N_ORIG
    float*  acc     = (float*)(overts4 + N_ORIG);    // 16 floats
    unsigned int* fwd_min = (unsigned int*)(acc + 16);   // F_SIMP
    unsigned int* rev_min = fwd_min + F_SIMP;            // NPTS

    int prepN = max(max(NPTS, F_ORIG), N_ORIG);
    hipLaunchKernelGGL(prep_kernel, dim3((prepN + BLK - 1) / BLK), dim3(BLK), 0, stream,
                       overts, ofaces, obc4, overts4, fwd_min, rev_min, acc,
                       N_ORIG, F_ORIG, F_SIMP, NPTS);

    // fwd: 2 point-blocks x 64 chunks = 128 blocks (chunk=250 verts)
    // rev: 16 point-blocks x 32 chunks = 512 blocks (chunk=250 verts)
    const int fwdPtBlocks = (F_SIMP + BLK * P - 1) / (BLK * P);
    const int FWD_CHUNKS = 64;
    const int fwdChunk = (F_ORIG + FWD_CHUNKS - 1) / FWD_CHUNKS;
    const int fwdBlocks = fwdPtBlocks * FWD_CHUNKS;

    const int revPtBlocks = (NPTS + BLK * P - 1) / (BLK * P);
    const int REV_CHUNKS = 32;
    const int revChunk = (N_ORIG + REV_CHUNKS - 1) / REV_CHUNKS;
    const int revBlocks = revPtBlocks * REV_CHUNKS;

    hipLaunchKernelGGL(min_kernel, dim3(fwdBlocks + revBlocks), dim3(BLK), 0, stream,
                       sverts, sfaces, u1, u2, obc4, overts4, fwd_min, rev_min,
                       F_SIMP, S,
                       fwdBlocks, fwdPtBlocks, fwdChunk, F_ORIG,
                       revPtBlocks, revChunk, N_ORIG);

    hipLaunchKernelGGL(finalize_partial_kernel, dim3((NPTS + BLK - 1) / BLK), dim3(BLK), 0, stream,
                       fwd_min, rev_min, fp, acc, F_SIMP, NPTS, S);

    hipLaunchKernelGGL(write_out_kernel, dim3(1), dim3(1), 0, stream, acc, out);
}